// Round 2
// baseline (20977.318 us; speedup 1.0000x reference)
//
#include <hip/hip_runtime.h>
#include <stdint.h>

#define BATCH 64
#define SEQ   2048
#define ISZ   512
#define HSZ   512
#define FH    2048   // 4*H

// workspace layout
#define FLAG_OFF 0                                  // 8 groups * 32 uints = 1KB
#define HBUF_OFF 65536                              // 2 * 64*512*4 = 256KB
#define CBUF_OFF (65536 + 2*BATCH*HSZ*4)            // 128KB
#define XG_OFF   ((size_t)1 << 20)                  // xg chunk buffer

// ---------------------------------------------------------------------------
// Phase 1: xg[(t-t0)*64 + b][j] = x[b][t][:] . Wx[:,j] + (b_x[j] + b_h[j])
// Tiles: 64(M=batch)x64(N), BK=32, 4x4 micro-tile, fp32 VALU.
// grid = (32 n-tiles, nsteps), 256 threads.
// ---------------------------------------------------------------------------
__global__ __launch_bounds__(256) void xg_gemm(
    const float* __restrict__ x,
    const float* __restrict__ Wx0, const float* __restrict__ Wx1,
    const float* __restrict__ Wx2, const float* __restrict__ Wx3,
    const float* __restrict__ bx0, const float* __restrict__ bx1,
    const float* __restrict__ bx2, const float* __restrict__ bx3,
    const float* __restrict__ bh0, const float* __restrict__ bh1,
    const float* __restrict__ bh2, const float* __restrict__ bh3,
    float* __restrict__ xg, int t0)
{
  __shared__ float Al[32 * 68];   // [k][b], padded stride 68
  __shared__ float Bl[32 * 68];   // [k][n], padded stride 68

  const int bxn = blockIdx.x;          // n-tile 0..31
  const int tl  = blockIdx.y;          // local t
  const int t   = t0 + tl;
  const int tid = threadIdx.x;
  const int gate = bxn >> 3;           // 0..3 (i,f,g,o)
  const int u0   = (bxn & 7) * 64;     // col within gate

  const float* Wg  = gate == 0 ? Wx0 : gate == 1 ? Wx1 : gate == 2 ? Wx2 : Wx3;
  const float* bxp = gate == 0 ? bx0 : gate == 1 ? bx1 : gate == 2 ? bx2 : bx3;
  const float* bhp = gate == 0 ? bh0 : gate == 1 ? bh1 : gate == 2 ? bh2 : bh3;

  const int tm = tid >> 4;             // 0..15 row quad
  const int tn = tid & 15;             // 0..15 col quad

  // staging roles
  const int ab = tid >> 2;             // 0..63  batch row (A)
  const int aq = tid & 3;
  const int bk = tid >> 3;             // 0..31  k row (B)
  const int bo = tid & 7;

  const float* xrow = x + ((size_t)ab * SEQ + t) * ISZ;

  float4 z = make_float4(0.f, 0.f, 0.f, 0.f);
  float4 acc0 = z, acc1 = z, acc2 = z, acc3 = z;

  for (int kb = 0; kb < 16; ++kb) {
    const int k0 = kb * 32;
    __syncthreads();
    // stage A (x tile, transposed to [k][b])
    {
      float4 v0 = *(const float4*)&xrow[k0 + aq * 4];
      float4 v1 = *(const float4*)&xrow[k0 + aq * 4 + 16];
      Al[(aq * 4 + 0) * 68 + ab] = v0.x;
      Al[(aq * 4 + 1) * 68 + ab] = v0.y;
      Al[(aq * 4 + 2) * 68 + ab] = v0.z;
      Al[(aq * 4 + 3) * 68 + ab] = v0.w;
      Al[(aq * 4 + 16) * 68 + ab] = v1.x;
      Al[(aq * 4 + 17) * 68 + ab] = v1.y;
      Al[(aq * 4 + 18) * 68 + ab] = v1.z;
      Al[(aq * 4 + 19) * 68 + ab] = v1.w;
    }
    // stage B (Wx tile)
    {
      const float* wrow = Wg + (size_t)(k0 + bk) * HSZ + u0;
      *(float4*)&Bl[bk * 68 + bo * 4]      = *(const float4*)&wrow[bo * 4];
      *(float4*)&Bl[bk * 68 + bo * 4 + 32] = *(const float4*)&wrow[bo * 4 + 32];
    }
    __syncthreads();
    #pragma unroll
    for (int kk = 0; kk < 32; ++kk) {
      float4 av = *(const float4*)&Al[kk * 68 + tm * 4];
      float4 bv = *(const float4*)&Bl[kk * 68 + tn * 4];
      acc0.x += av.x * bv.x; acc0.y += av.x * bv.y; acc0.z += av.x * bv.z; acc0.w += av.x * bv.w;
      acc1.x += av.y * bv.x; acc1.y += av.y * bv.y; acc1.z += av.y * bv.z; acc1.w += av.y * bv.w;
      acc2.x += av.z * bv.x; acc2.y += av.z * bv.y; acc2.z += av.z * bv.z; acc2.w += av.z * bv.w;
      acc3.x += av.w * bv.x; acc3.y += av.w * bv.y; acc3.z += av.w * bv.z; acc3.w += av.w * bv.w;
    }
  }

  float4 bb;
  bb.x = bxp[u0 + tn * 4 + 0] + bhp[u0 + tn * 4 + 0];
  bb.y = bxp[u0 + tn * 4 + 1] + bhp[u0 + tn * 4 + 1];
  bb.z = bxp[u0 + tn * 4 + 2] + bhp[u0 + tn * 4 + 2];
  bb.w = bxp[u0 + tn * 4 + 3] + bhp[u0 + tn * 4 + 3];

  acc0.x += bb.x; acc0.y += bb.y; acc0.z += bb.z; acc0.w += bb.w;
  acc1.x += bb.x; acc1.y += bb.y; acc1.z += bb.z; acc1.w += bb.w;
  acc2.x += bb.x; acc2.y += bb.y; acc2.z += bb.z; acc2.w += bb.w;
  acc3.x += bb.x; acc3.y += bb.y; acc3.z += bb.z; acc3.w += bb.w;

  size_t base = ((size_t)tl * BATCH + tm * 4) * FH + bxn * 64 + tn * 4;
  *(float4*)&xg[base]          = acc0;
  *(float4*)&xg[base + FH]     = acc1;
  *(float4*)&xg[base + 2 * FH] = acc2;
  *(float4*)&xg[base + 3 * FH] = acc3;
}

// ---------------------------------------------------------------------------
// Phase 2: persistent recurrent scan.
// 256 WGs x 512 threads. WG (hg,bg): bg=bid&7 -> batch rows [bg*8, bg*8+8),
// hg=bid>>3 -> hidden units [hg*16, hg*16+16) (64 gate columns).
// Wh slice (512x64 = 128KB) lives in dynamic LDS for the whole kernel.
// Per-step barrier: only among the 32 WGs sharing bg (independent chains),
// leaderless 32-flag line poll, agent-scope (L3-pinned) atomics, no
// __threadfence (avoids per-step bulk L2 writeback/invalidate).
// ---------------------------------------------------------------------------
__global__ __launch_bounds__(512) void lstm_scan(
    const float* __restrict__ Wh0, const float* __restrict__ Wh1,
    const float* __restrict__ Wh2, const float* __restrict__ Wh3,
    const float* __restrict__ xg, float* __restrict__ hbuf,
    float* __restrict__ cbuf, unsigned* __restrict__ flags_base,
    float* __restrict__ out, int t0, int nsteps)
{
  extern __shared__ float Whl[];      // [512][64] = 128KB
  __shared__ float hred[4160];        // h stage [8][516] padded / partials [8][8][64]
  __shared__ float gates_s[512];      // [8 rows][64 cols]
  __shared__ float cs[128];           // [8 rows][16 units]

  const int bid = blockIdx.x;
  const int bg = bid & 7;
  const int hg = bid >> 3;
  const int b0 = bg * 8;
  const int u0 = hg * 16;
  const int tid = threadIdx.x;

  unsigned* flags = flags_base + bg * 32;   // one 128B line per batch group

  // ---- one-time: stage Wh slice into LDS -------------------------------
  {
    const int cq = tid & 15;          // col quad 0..15 ; gate = cq>>2
    const int kr = tid >> 4;          // 0..31
    const float* Wg = (cq >> 2) == 0 ? Wh0 : (cq >> 2) == 1 ? Wh1
                    : (cq >> 2) == 2 ? Wh2 : Wh3;
    const int uoff = u0 + (cq & 3) * 4;
    #pragma unroll
    for (int ii = 0; ii < 16; ++ii) {
      int k = kr + 32 * ii;
      float4 v = *(const float4*)&Wg[(size_t)k * HSZ + uoff];
      *(float4*)&Whl[k * 64 + cq * 4] = v;
    }
  }
  // load persistent c slice
  if (tid < 128) cs[tid] = cbuf[(b0 + (tid >> 4)) * HSZ + u0 + (tid & 15)];
  __syncthreads();

  const int cg = tid & 15;            // col quad
  const int rg = (tid >> 4) & 3;      // row pair
  const int ks = tid >> 6;            // k split 0..7
  float* hr0 = &hred[(rg * 2) * 516];
  float* hr1 = hr0 + 516;

  for (int st = 0; st < nsteps; ++st) {
    const int t = t0 + st;
    const int par = t & 1;

    // ---- stage h rows [b0, b0+8) : 4096 floats, agent-scope (L3) loads ----
    {
      const unsigned long long* src =
          (const unsigned long long*)(hbuf + (size_t)par * BATCH * HSZ + b0 * HSZ);
      #pragma unroll
      for (int i = 0; i < 4; ++i) {
        int idx2 = tid + i * 512;                  // 0..2047 (8B units)
        unsigned long long v =
            __hip_atomic_load(&src[idx2], __ATOMIC_RELAXED, __HIP_MEMORY_SCOPE_AGENT);
        int r = idx2 >> 8;
        int k = (idx2 & 255) * 2;
        float2 fv;
        fv.x = __uint_as_float((unsigned)(v & 0xffffffffu));
        fv.y = __uint_as_float((unsigned)(v >> 32));
        *(float2*)&hred[r * 516 + k] = fv;
      }
    }
    __syncthreads();

    // ---- K-loop: gates[2 rows][4 cols] partial over 64 k ----
    float a00 = 0.f, a01 = 0.f, a02 = 0.f, a03 = 0.f;
    float a10 = 0.f, a11 = 0.f, a12 = 0.f, a13 = 0.f;
    const int kb = ks * 64;
    #pragma unroll 8
    for (int kk = 0; kk < 64; ++kk) {
      int k = kb + kk;
      float4 w = *(const float4*)&Whl[k * 64 + cg * 4];
      float h0 = hr0[k];
      float h1 = hr1[k];
      a00 += h0 * w.x; a01 += h0 * w.y; a02 += h0 * w.z; a03 += h0 * w.w;
      a10 += h1 * w.x; a11 += h1 * w.y; a12 += h1 * w.z; a13 += h1 * w.w;
    }
    __syncthreads();   // done reading hred

    // ---- write partials (reuse hred as [ks][8][64]) ----
    *(float4*)&hred[ks * 512 + (rg * 2) * 64 + cg * 4] = make_float4(a00, a01, a02, a03);
    *(float4*)&hred[ks * 512 + (rg * 2 + 1) * 64 + cg * 4] = make_float4(a10, a11, a12, a13);
    __syncthreads();

    // ---- reduce 8 partials + xg + bias-folded input projection ----
    {
      int r = tid >> 6, c = tid & 63;
      float s = 0.f;
      #pragma unroll
      for (int q = 0; q < 8; ++q) s += hred[q * 512 + r * 64 + c];
      int g = c >> 4, uu = c & 15;
      s += xg[(size_t)st * BATCH * FH + (size_t)(b0 + r) * FH + g * HSZ + u0 + uu];
      gates_s[r * 64 + c] = s;
    }
    __syncthreads();

    // ---- cell update (128 cells) ----
    if (tid < 128) {
      int r = tid >> 4, uu = tid & 15;
      float gi = gates_s[r * 64 + uu];
      float gf = gates_s[r * 64 + 16 + uu];
      float gg = gates_s[r * 64 + 32 + uu];
      float go = gates_s[r * 64 + 48 + uu];
      float si = 1.f / (1.f + expf(-gi));
      float sf = 1.f / (1.f + expf(-gf));
      float tg = tanhf(gg);
      float so = 1.f / (1.f + expf(-go));
      float cn = sf * cs[tid] + si * tg;
      float hn = so * tanhf(cn);
      cs[tid] = cn;
      // h to the other parity buffer, write-through to L3 (agent scope)
      __hip_atomic_store(&hbuf[(size_t)(par ^ 1) * BATCH * HSZ + (size_t)(b0 + r) * HSZ + u0 + uu],
                         hn, __ATOMIC_RELAXED, __HIP_MEMORY_SCOPE_AGENT);
      if (t == SEQ - 1) {
        out[(b0 + r) * HSZ + u0 + uu] = hn;                     // h_t
        out[BATCH * HSZ + (b0 + r) * HSZ + u0 + uu] = cn;       // c_t
      }
    }
    // make sure this wave's h stores reached L3 before anyone signals
    asm volatile("s_waitcnt vmcnt(0)" ::: "memory");
    __syncthreads();

    // ---- leaderless barrier among the 32 WGs of this batch group ----
    if (tid == 0) {
      unsigned target = (unsigned)(t + 1);
      __hip_atomic_store(&flags[hg], target, __ATOMIC_RELAXED, __HIP_MEMORY_SCOPE_AGENT);
      for (;;) {
        unsigned mn = 0xffffffffu;
        #pragma unroll
        for (int q = 0; q < 32; ++q) {
          unsigned v = __hip_atomic_load(&flags[q], __ATOMIC_RELAXED, __HIP_MEMORY_SCOPE_AGENT);
          mn = v < mn ? v : mn;
        }
        if (mn >= target) break;
        __builtin_amdgcn_s_sleep(2);
      }
    }
    __syncthreads();
  }

  // persist c slice for next chunk
  if (tid < 128) cbuf[(b0 + (tid >> 4)) * HSZ + u0 + (tid & 15)] = cs[tid];
}

// ---------------------------------------------------------------------------
extern "C" void kernel_launch(void* const* d_in, const int* in_sizes, int n_in,
                              void* d_out, int out_size, void* d_ws, size_t ws_size,
                              hipStream_t stream) {
  (void)in_sizes; (void)n_in; (void)out_size;
  const float* x = (const float*)d_in[0];
  const float* Wx[4] = {(const float*)d_in[1], (const float*)d_in[5],
                        (const float*)d_in[9], (const float*)d_in[13]};
  const float* Wh[4] = {(const float*)d_in[2], (const float*)d_in[6],
                        (const float*)d_in[10], (const float*)d_in[14]};
  const float* bx[4] = {(const float*)d_in[3], (const float*)d_in[7],
                        (const float*)d_in[11], (const float*)d_in[15]};
  const float* bh[4] = {(const float*)d_in[4], (const float*)d_in[8],
                        (const float*)d_in[12], (const float*)d_in[16]};
  float* out = (float*)d_out;
  char* ws = (char*)d_ws;

  unsigned* flags = (unsigned*)(ws + FLAG_OFF);
  float* hbuf = (float*)(ws + HBUF_OFF);
  float* cbuf = (float*)(ws + CBUF_OFF);
  float* xgbuf = (float*)(ws + XG_OFF);

  // allow 128KB dynamic LDS for the scan kernel (idempotent, not a stream op)
  hipFuncSetAttribute((const void*)lstm_scan,
                      hipFuncAttributeMaxDynamicSharedMemorySize, 131072);

  // zero flags + h/c state (ws is poisoned 0xAA before every call)
  hipMemsetAsync(d_ws, 0, (size_t)1 << 20, stream);

  const size_t per_step = (size_t)BATCH * FH * sizeof(float);   // 512KB
  size_t avail = ws_size > XG_OFF ? ws_size - XG_OFF : 0;
  int Sc = (int)(avail / per_step);
  if (Sc > SEQ) Sc = SEQ;
  if (Sc < 1) return;   // workspace too small to run

  for (int t0 = 0; t0 < SEQ; t0 += Sc) {
    int ns = (SEQ - t0 < Sc) ? (SEQ - t0) : Sc;
    xg_gemm<<<dim3(32, ns), 256, 0, stream>>>(
        x, Wx[0], Wx[1], Wx[2], Wx[3],
        bx[0], bx[1], bx[2], bx[3],
        bh[0], bh[1], bh[2], bh[3],
        xgbuf, t0);

    const float* a0 = Wh[0]; const float* a1 = Wh[1];
    const float* a2 = Wh[2]; const float* a3 = Wh[3];
    const float* xgp = xgbuf;
    float* hbp = hbuf; float* cbp = cbuf; unsigned* flp = flags;
    float* outp = out;
    int t0v = t0, nsv = ns;
    void* args[] = {&a0, &a1, &a2, &a3, &xgp, &hbp, &cbp, &flp, &outp, &t0v, &nsv};
    hipLaunchCooperativeKernel((const void*)lstm_scan, dim3(256), dim3(512),
                               args, 131072, stream);
  }
}

// Round 3
// 15168.797 us; speedup vs baseline: 1.3829x; 1.3829x over previous
//
#include <hip/hip_runtime.h>
#include <stdint.h>

#define BATCH 64
#define SEQ   2048
#define ISZ   512
#define HSZ   512
#define FH    2048   // 4*H

// workspace layout
#define FLAG_OFF 0                                  // 8 groups * 32 uints = 1KB
#define HBUF_OFF 65536                              // 2 * 64*512*4 = 256KB
#define CBUF_OFF (65536 + 2*BATCH*HSZ*4)            // 128KB
#define XG_OFF   ((size_t)1 << 20)                  // xg chunk buffer

// ---------------------------------------------------------------------------
// Phase 1: xg[(t-t0)*64 + b][j] = x[b][t][:] . Wx[:,j] + (b_x[j] + b_h[j])
// (unchanged from round 2 — known-good)
// ---------------------------------------------------------------------------
__global__ __launch_bounds__(256) void xg_gemm(
    const float* __restrict__ x,
    const float* __restrict__ Wx0, const float* __restrict__ Wx1,
    const float* __restrict__ Wx2, const float* __restrict__ Wx3,
    const float* __restrict__ bx0, const float* __restrict__ bx1,
    const float* __restrict__ bx2, const float* __restrict__ bx3,
    const float* __restrict__ bh0, const float* __restrict__ bh1,
    const float* __restrict__ bh2, const float* __restrict__ bh3,
    float* __restrict__ xg, int t0)
{
  __shared__ float Al[32 * 68];   // [k][b], padded stride 68
  __shared__ float Bl[32 * 68];   // [k][n], padded stride 68

  const int bxn = blockIdx.x;          // n-tile 0..31
  const int tl  = blockIdx.y;          // local t
  const int t   = t0 + tl;
  const int tid = threadIdx.x;
  const int gate = bxn >> 3;           // 0..3 (i,f,g,o)
  const int u0   = (bxn & 7) * 64;     // col within gate

  const float* Wg  = gate == 0 ? Wx0 : gate == 1 ? Wx1 : gate == 2 ? Wx2 : Wx3;
  const float* bxp = gate == 0 ? bx0 : gate == 1 ? bx1 : gate == 2 ? bx2 : bx3;
  const float* bhp = gate == 0 ? bh0 : gate == 1 ? bh1 : gate == 2 ? bh2 : bh3;

  const int tm = tid >> 4;             // 0..15 row quad
  const int tn = tid & 15;             // 0..15 col quad

  // staging roles
  const int ab = tid >> 2;             // 0..63  batch row (A)
  const int aq = tid & 3;
  const int bk = tid >> 3;             // 0..31  k row (B)
  const int bo = tid & 7;

  const float* xrow = x + ((size_t)ab * SEQ + t) * ISZ;

  float4 z = make_float4(0.f, 0.f, 0.f, 0.f);
  float4 acc0 = z, acc1 = z, acc2 = z, acc3 = z;

  for (int kb = 0; kb < 16; ++kb) {
    const int k0 = kb * 32;
    __syncthreads();
    // stage A (x tile, transposed to [k][b])
    {
      float4 v0 = *(const float4*)&xrow[k0 + aq * 4];
      float4 v1 = *(const float4*)&xrow[k0 + aq * 4 + 16];
      Al[(aq * 4 + 0) * 68 + ab] = v0.x;
      Al[(aq * 4 + 1) * 68 + ab] = v0.y;
      Al[(aq * 4 + 2) * 68 + ab] = v0.z;
      Al[(aq * 4 + 3) * 68 + ab] = v0.w;
      Al[(aq * 4 + 16) * 68 + ab] = v1.x;
      Al[(aq * 4 + 17) * 68 + ab] = v1.y;
      Al[(aq * 4 + 18) * 68 + ab] = v1.z;
      Al[(aq * 4 + 19) * 68 + ab] = v1.w;
    }
    // stage B (Wx tile)
    {
      const float* wrow = Wg + (size_t)(k0 + bk) * HSZ + u0;
      *(float4*)&Bl[bk * 68 + bo * 4]      = *(const float4*)&wrow[bo * 4];
      *(float4*)&Bl[bk * 68 + bo * 4 + 32] = *(const float4*)&wrow[bo * 4 + 32];
    }
    __syncthreads();
    #pragma unroll
    for (int kk = 0; kk < 32; ++kk) {
      float4 av = *(const float4*)&Al[kk * 68 + tm * 4];
      float4 bv = *(const float4*)&Bl[kk * 68 + tn * 4];
      acc0.x += av.x * bv.x; acc0.y += av.x * bv.y; acc0.z += av.x * bv.z; acc0.w += av.x * bv.w;
      acc1.x += av.y * bv.x; acc1.y += av.y * bv.y; acc1.z += av.y * bv.z; acc1.w += av.y * bv.w;
      acc2.x += av.z * bv.x; acc2.y += av.z * bv.y; acc2.z += av.z * bv.z; acc2.w += av.z * bv.w;
      acc3.x += av.w * bv.x; acc3.y += av.w * bv.y; acc3.z += av.w * bv.z; acc3.w += av.w * bv.w;
    }
  }

  float4 bb;
  bb.x = bxp[u0 + tn * 4 + 0] + bhp[u0 + tn * 4 + 0];
  bb.y = bxp[u0 + tn * 4 + 1] + bhp[u0 + tn * 4 + 1];
  bb.z = bxp[u0 + tn * 4 + 2] + bhp[u0 + tn * 4 + 2];
  bb.w = bxp[u0 + tn * 4 + 3] + bhp[u0 + tn * 4 + 3];

  acc0.x += bb.x; acc0.y += bb.y; acc0.z += bb.z; acc0.w += bb.w;
  acc1.x += bb.x; acc1.y += bb.y; acc1.z += bb.z; acc1.w += bb.w;
  acc2.x += bb.x; acc2.y += bb.y; acc2.z += bb.z; acc2.w += bb.w;
  acc3.x += bb.x; acc3.y += bb.y; acc3.z += bb.z; acc3.w += bb.w;

  size_t base = ((size_t)tl * BATCH + tm * 4) * FH + bxn * 64 + tn * 4;
  *(float4*)&xg[base]          = acc0;
  *(float4*)&xg[base + FH]     = acc1;
  *(float4*)&xg[base + 2 * FH] = acc2;
  *(float4*)&xg[base + 3 * FH] = acc3;
}

// ---------------------------------------------------------------------------
// Phase 2: persistent recurrent scan, Wh in REGISTERS (no LDS Wh).
// 256 WGs x 512 threads. WG (hg,bg): bg=bid&7 -> batch rows [bg*8,+8),
// hg=bid>>3 -> hidden units [hg*16,+16) = 64 gate columns.
// Lane layout: cg = tid&15 -> 4 gate cols (cg*4..+3 within the WG's 64);
// kst = tid>>4 (0..31) -> k-slice [kst*16, +16). Each lane holds
// wreg[16] float4 (its Wh block, 64 VGPRs) loaded once from global.
// Per step: stage h (16KB) in LDS -> K-loop (h broadcast b128 reads,
// conflict-free) -> 32-way partial reduce via 64KB dynamic-LDS buffer ->
// gates -> cell update -> h to L3 -> per-chain flag barrier.
// xg gate-projections prefetched one step ahead into registers.
// ---------------------------------------------------------------------------
__global__ __launch_bounds__(512, 2) void lstm_scan(
    const float* __restrict__ Wh0, const float* __restrict__ Wh1,
    const float* __restrict__ Wh2, const float* __restrict__ Wh3,
    const float* __restrict__ xg, float* __restrict__ hbuf,
    float* __restrict__ cbuf, unsigned* __restrict__ flags_base,
    float* __restrict__ out, int t0, int nsteps)
{
  extern __shared__ float hred2[];    // [32][512] = 64KB dynamic (partials)
  __shared__ float hstage[8 * 516];   // h rows, padded stride 516 (16.5KB)
  __shared__ float gates_s[512];      // [8 rows][64 cols]
  __shared__ float cs[128];           // [8 rows][16 units]

  const int bid = blockIdx.x;
  const int bg = bid & 7;
  const int hg = bid >> 3;
  const int b0 = bg * 8;
  const int u0 = hg * 16;
  const int tid = threadIdx.x;
  const int cg  = tid & 15;           // col quad 0..15
  const int kst = tid >> 4;           // k-slice 0..31
  const int kb  = kst * 16;           // k base for this lane

  unsigned* flags = flags_base + bg * 32;   // one 128B line per batch group

  // ---- one-time: Wh block into registers (64 VGPRs) --------------------
  const int gate = cg >> 2;
  const float* Wg = gate == 0 ? Wh0 : gate == 1 ? Wh1 : gate == 2 ? Wh2 : Wh3;
  const int colg = u0 + (cg & 3) * 4;
  float4 wreg[16];
  #pragma unroll
  for (int j = 0; j < 16; ++j)
    wreg[j] = *(const float4*)&Wg[(size_t)(kb + j) * HSZ + colg];

  // persistent c slice
  if (tid < 128) cs[tid] = cbuf[(b0 + (tid >> 4)) * HSZ + u0 + (tid & 15)];

  // xg address for this thread: (row b0 + tid>>6, gate (tid>>4)&3, unit tid&15)
  const size_t xgoff = (size_t)(b0 + (tid >> 6)) * FH
                     + (size_t)((tid >> 4) & 3) * HSZ + u0 + (tid & 15);
  float xg_c = xg[xgoff];             // st = 0
  float xg_n = xg_c;

  for (int st = 0; st < nsteps; ++st) {
    const int t = t0 + st;
    const int par = t & 1;

    // ---- stage h rows [b0, b0+8): 16KB, agent-scope (L3) loads ----
    {
      const unsigned long long* src =
          (const unsigned long long*)(hbuf + (size_t)par * BATCH * HSZ + b0 * HSZ);
      #pragma unroll
      for (int i = 0; i < 4; ++i) {
        int idx2 = tid + i * 512;                  // 0..2047 (8B units)
        unsigned long long v =
            __hip_atomic_load(&src[idx2], __ATOMIC_RELAXED, __HIP_MEMORY_SCOPE_AGENT);
        int r = idx2 >> 8;
        int k = (idx2 & 255) * 2;
        float2 fv;
        fv.x = __uint_as_float((unsigned)(v & 0xffffffffu));
        fv.y = __uint_as_float((unsigned)(v >> 32));
        *(float2*)&hstage[r * 516 + k] = fv;
      }
    }
    // ---- prefetch xg for next step (hidden under K-loop) ----
    {
      int stn = (st + 1 < nsteps) ? st + 1 : st;
      xg_n = xg[(size_t)stn * BATCH * FH + xgoff];
    }
    __syncthreads();

    // ---- K-loop: 8 rows x 4 cols x 16 k per lane, Wh in regs ----
    float4 acc[8];
    #pragma unroll
    for (int r = 0; r < 8; ++r) acc[r] = make_float4(0.f, 0.f, 0.f, 0.f);
    #pragma unroll
    for (int jq = 0; jq < 4; ++jq) {
      float4 hv[8];
      #pragma unroll
      for (int r = 0; r < 8; ++r)
        hv[r] = *(const float4*)&hstage[r * 516 + kb + jq * 4];
      const float4 w0 = wreg[jq * 4 + 0];
      const float4 w1 = wreg[jq * 4 + 1];
      const float4 w2 = wreg[jq * 4 + 2];
      const float4 w3 = wreg[jq * 4 + 3];
      #pragma unroll
      for (int r = 0; r < 8; ++r) {
        acc[r].x += hv[r].x * w0.x; acc[r].y += hv[r].x * w0.y;
        acc[r].z += hv[r].x * w0.z; acc[r].w += hv[r].x * w0.w;
        acc[r].x += hv[r].y * w1.x; acc[r].y += hv[r].y * w1.y;
        acc[r].z += hv[r].y * w1.z; acc[r].w += hv[r].y * w1.w;
        acc[r].x += hv[r].z * w2.x; acc[r].y += hv[r].z * w2.y;
        acc[r].z += hv[r].z * w2.z; acc[r].w += hv[r].z * w2.w;
        acc[r].x += hv[r].w * w3.x; acc[r].y += hv[r].w * w3.y;
        acc[r].z += hv[r].w * w3.z; acc[r].w += hv[r].w * w3.w;
      }
    }

    // ---- write 32-way partials: hred2[kst][r][cg*4..+3] ----
    #pragma unroll
    for (int r = 0; r < 8; ++r)
      *(float4*)&hred2[kst * 512 + r * 64 + cg * 4] = acc[r];
    __syncthreads();

    // ---- reduce 32 partials + prefetched xg -> gates ----
    {
      float s = 0.f;
      #pragma unroll
      for (int q = 0; q < 32; ++q) s += hred2[q * 512 + tid];
      gates_s[tid] = s + xg_c;
    }
    __syncthreads();

    // ---- cell update (128 cells) ----
    if (tid < 128) {
      int r = tid >> 4, uu = tid & 15;
      float gi = gates_s[r * 64 + uu];
      float gf = gates_s[r * 64 + 16 + uu];
      float gg = gates_s[r * 64 + 32 + uu];
      float go = gates_s[r * 64 + 48 + uu];
      float si = 1.f / (1.f + expf(-gi));
      float sf = 1.f / (1.f + expf(-gf));
      float tg = tanhf(gg);
      float so = 1.f / (1.f + expf(-go));
      float cn = sf * cs[tid] + si * tg;
      float hn = so * tanhf(cn);
      cs[tid] = cn;
      // h to the other parity buffer, write-through to L3 (agent scope)
      __hip_atomic_store(&hbuf[(size_t)(par ^ 1) * BATCH * HSZ + (size_t)(b0 + r) * HSZ + u0 + uu],
                         hn, __ATOMIC_RELAXED, __HIP_MEMORY_SCOPE_AGENT);
      if (t == SEQ - 1) {
        out[(b0 + r) * HSZ + u0 + uu] = hn;                     // h_t
        out[BATCH * HSZ + (b0 + r) * HSZ + u0 + uu] = cn;       // c_t
      }
    }
    // this wave's h stores must reach L3 before anyone signals
    asm volatile("s_waitcnt vmcnt(0)" ::: "memory");
    __syncthreads();

    // ---- leaderless barrier among the 32 WGs of this batch group ----
    if (tid < 64) {
      unsigned target = (unsigned)(t + 1);
      if (tid == 0)
        __hip_atomic_store(&flags[hg], target, __ATOMIC_RELAXED, __HIP_MEMORY_SCOPE_AGENT);
      for (;;) {
        unsigned v = target;
        if (tid < 32)
          v = __hip_atomic_load(&flags[tid], __ATOMIC_RELAXED, __HIP_MEMORY_SCOPE_AGENT);
        if (__all((int)(v >= target))) break;
        __builtin_amdgcn_s_sleep(1);
      }
    }
    __syncthreads();

    xg_c = xg_n;
  }

  // persist c slice for next chunk
  if (tid < 128) cbuf[(b0 + (tid >> 4)) * HSZ + u0 + (tid & 15)] = cs[tid];
}

// ---------------------------------------------------------------------------
extern "C" void kernel_launch(void* const* d_in, const int* in_sizes, int n_in,
                              void* d_out, int out_size, void* d_ws, size_t ws_size,
                              hipStream_t stream) {
  (void)in_sizes; (void)n_in; (void)out_size;
  const float* x = (const float*)d_in[0];
  const float* Wx[4] = {(const float*)d_in[1], (const float*)d_in[5],
                        (const float*)d_in[9], (const float*)d_in[13]};
  const float* Wh[4] = {(const float*)d_in[2], (const float*)d_in[6],
                        (const float*)d_in[10], (const float*)d_in[14]};
  const float* bx[4] = {(const float*)d_in[3], (const float*)d_in[7],
                        (const float*)d_in[11], (const float*)d_in[15]};
  const float* bh[4] = {(const float*)d_in[4], (const float*)d_in[8],
                        (const float*)d_in[12], (const float*)d_in[16]};
  float* out = (float*)d_out;
  char* ws = (char*)d_ws;

  unsigned* flags = (unsigned*)(ws + FLAG_OFF);
  float* hbuf = (float*)(ws + HBUF_OFF);
  float* cbuf = (float*)(ws + CBUF_OFF);
  float* xgbuf = (float*)(ws + XG_OFF);

  // allow 64KB dynamic LDS for the scan kernel (idempotent, not a stream op)
  hipFuncSetAttribute((const void*)lstm_scan,
                      hipFuncAttributeMaxDynamicSharedMemorySize, 65536);

  // zero flags + h/c state (ws is poisoned 0xAA before every call)
  hipMemsetAsync(d_ws, 0, (size_t)1 << 20, stream);

  const size_t per_step = (size_t)BATCH * FH * sizeof(float);   // 512KB
  size_t avail = ws_size > XG_OFF ? ws_size - XG_OFF : 0;
  int Sc = (int)(avail / per_step);
  if (Sc > SEQ) Sc = SEQ;
  if (Sc < 1) return;   // workspace too small to run

  for (int t0 = 0; t0 < SEQ; t0 += Sc) {
    int ns = (SEQ - t0 < Sc) ? (SEQ - t0) : Sc;
    xg_gemm<<<dim3(32, ns), 256, 0, stream>>>(
        x, Wx[0], Wx[1], Wx[2], Wx[3],
        bx[0], bx[1], bx[2], bx[3],
        bh[0], bh[1], bh[2], bh[3],
        xgbuf, t0);

    const float* a0 = Wh[0]; const float* a1 = Wh[1];
    const float* a2 = Wh[2]; const float* a3 = Wh[3];
    const float* xgp = xgbuf;
    float* hbp = hbuf; float* cbp = cbuf; unsigned* flp = flags;
    float* outp = out;
    int t0v = t0, nsv = ns;
    void* args[] = {&a0, &a1, &a2, &a3, &xgp, &hbp, &cbp, &flp, &outp, &t0v, &nsv};
    hipLaunchCooperativeKernel((const void*)lstm_scan, dim3(256), dim3(512),
                               args, 65536, stream);
  }
}